// Round 12
// baseline (512.745 us; speedup 1.0000x reference)
//
#include <hip/hip_runtime.h>

// Problem constants (reference: B=16, Q=2048, K=2048, D=128, fp32, NEG=-1e6)
constexpr int NB = 16;
constexpr int NQ = 2048;
constexpr int NK = 2048;
constexpr int ND = 128;
constexpr int KVBLK = 64;                 // kv per tile
constexpr int NTILE = NK / KVBLK;         // 32
constexpr int TILE_USH = KVBLK * ND;      // 8192 ushorts = 16KB per tile
constexpr float SCALE = 0.08838834764831844f; // 1/sqrt(128)

typedef __attribute__((ext_vector_type(4))) float f4;
typedef __attribute__((ext_vector_type(16))) float f32x16;
typedef __attribute__((ext_vector_type(4))) unsigned short us4;
typedef __attribute__((ext_vector_type(8))) unsigned short us8;
typedef __attribute__((ext_vector_type(8))) __bf16 bf16x8;
typedef __attribute__((ext_vector_type(4))) unsigned int u32x4;

static __device__ __forceinline__ unsigned short f2bf(float f) {
    unsigned u = __builtin_bit_cast(unsigned, f);
    u += 0x7fffu + ((u >> 16) & 1u);
    return (unsigned short)(u >> 16);
}
static __device__ __forceinline__ float bf2f(unsigned short u) {
    return __builtin_bit_cast(float, (unsigned)u << 16);
}
static __device__ __forceinline__ f4 splat4(float x) { f4 r = {x,x,x,x}; return r; }

static __device__ __forceinline__ void load_lds16(const unsigned short* g, unsigned short* l) {
    __builtin_amdgcn_global_load_lds(
        (const __attribute__((address_space(1))) void*)g,
        (__attribute__((address_space(3))) void*)l,
        16, 0, 0);
}

static __device__ __forceinline__ unsigned cvt_pk_bf16(float lo, float hi) {
    unsigned r;
    asm("v_cvt_pk_bf16_f32 %0, %1, %2" : "=v"(r) : "v"(lo), "v"(hi));
    return r;
}

// ---------------------------------------------------------------------------
// Prep: per (batch, kv-tile=64) write K and V in lane-linear 32x32-MFMA
// fragment order (verified R5-R11):
//  K  (kv,d): off = ((kv>>5)*8 + (d>>4))*512 + ((d>>3)&1)*256 + (kv&31)*8 + (d&7)
//  V  (kv,d): off = ((kv>>4)*4 + (d>>5))*512 + ((kv>>3)&1)*256 + (d&31)*8 + (kv&7)
// grid (NTILE, NB), 256 threads
// ---------------------------------------------------------------------------
__global__ __launch_bounds__(256)
void prep_kv4(const float* __restrict__ kg, const float* __restrict__ vg,
              unsigned short* __restrict__ wk, unsigned short* __restrict__ wvt)
{
    const int b   = blockIdx.y;
    const int t   = blockIdx.x;
    const int kv0 = t * KVBLK;
    const int t0  = threadIdx.x;

    __shared__ __align__(16) unsigned short vl[64 * 136];

    {
        const int kv = t0 >> 2;
        const int c  = t0 & 3;
        const float* gp = kg + (size_t)(b * NK + kv0 + kv) * ND + c * 32;
        unsigned short* ob = wk + (size_t)(b * NTILE + t) * TILE_USH;
        #pragma unroll
        for (int g = 0; g < 4; ++g) {
            f4 f0 = *(const f4*)(gp + g * 8);
            f4 f1 = *(const f4*)(gp + g * 8 + 4);
            us8 w;
            #pragma unroll
            for (int i = 0; i < 4; ++i) { w[i] = f2bf(f0[i]); w[i+4] = f2bf(f1[i]); }
            const int d0 = c * 32 + g * 8;
            const int f  = (kv >> 5) * 8 + (d0 >> 4);
            const int off = f * 512 + ((d0 >> 3) & 1) * 256 + (kv & 31) * 8;
            *(us8*)(ob + off) = w;
        }
    }
    {
        const int kv = t0 >> 2;
        const int d0 = (t0 & 3) * 32;
        const float* gp = vg + (size_t)(b * NK + kv0 + kv) * ND + d0;
        unsigned short* lb = &vl[kv * 136 + d0];
        #pragma unroll
        for (int g = 0; g < 4; ++g) {
            f4 f0 = *(const f4*)(gp + g * 8);
            f4 f1 = *(const f4*)(gp + g * 8 + 4);
            us8 w;
            #pragma unroll
            for (int i = 0; i < 4; ++i) { w[i] = f2bf(f0[i]); w[i+4] = f2bf(f1[i]); }
            *(us8*)(lb + g * 8) = w;
        }
    }
    __syncthreads();
    {
        unsigned short* ob = wvt + (size_t)(b * NTILE + t) * TILE_USH;
        #pragma unroll
        for (int iter = 0; iter < 4; ++iter) {
            const int cid = iter * 256 + t0;
            const int f   = cid >> 6;
            const int l   = cid & 63;
            const int kb  = (f >> 2) * 16 + (l >> 5) * 8;
            const int d   = (f & 3) * 32 + (l & 31);
            us8 w;
            #pragma unroll
            for (int j = 0; j < 8; ++j) w[j] = vl[(kb + j) * 136 + d];
            *(us8*)(ob + cid * 8) = w;
        }
    }
}

// ---------------------------------------------------------------------------
// Fused attention v12: ONE 1024-thr block per CU (grid=256), 4 KV-groups x
// 4 q-waves (QBLK=128). Group g handles tiles t%4==g in a 32KB rotated
// buffer; 16 waves stay resident (4/SIMD) until the block retires.
// Iterations = ceil(L/256). Epilogue: groups 1-3 -> bf16 partials in LDS,
// group 0 tree-merges and stores.
// ---------------------------------------------------------------------------
__global__ __launch_bounds__(1024, 4)
void attn_fused12(const float* __restrict__ qg, const int* __restrict__ vlen,
                  const unsigned short* __restrict__ wk,
                  const unsigned short* __restrict__ wvt,
                  float* __restrict__ og)
{
    const int bid = blockIdx.x;
    const int b   = bid & 15;      // XCD x hosts batches {x, x+8}: KV L2-resident
    const int qc  = bid >> 4;      // 0..15
    const int q0  = qc * 128;

    const int tid  = threadIdx.x;
    const int wid  = tid >> 6;     // 0..15
    const int grp  = wid >> 2;     // KV-group 0..3
    const int w4   = wid & 3;      // q-wave within group (32 rows each)
    const int lane = tid & 63;
    const int lq   = lane & 31;
    const int hi   = lane >> 5;

    const int L = vlen[b];
    const bool uniform = (L <= 0);
    const int Leff = uniform ? NK : L;
    const int ntiles = (Leff + KVBLK - 1) / KVBLK;
    const int ng    = (ntiles > grp) ? ((ntiles - grp + 3) >> 2) : 0;
    const int niter = (ntiles + 3) >> 2;

    // per-group 32KB single-rotated buffer: [K 16KB | V 16KB]; total 128KB
    __shared__ __align__(16) unsigned short smem[4][2 * TILE_USH];

    // ---- Q fragments (B-operand), scaled
    bf16x8 aq[8];
    {
        const float* qp = qg + (size_t)(b * NQ + q0 + w4 * 32 + lq) * ND + hi * 8;
        #pragma unroll
        for (int c = 0; c < 8; ++c) {
            f4 f0 = *(const f4*)(qp + c * 16);
            f4 f1 = *(const f4*)(qp + c * 16 + 4);
            us8 u;
            #pragma unroll
            for (int i = 0; i < 4; ++i) {
                u[i]     = f2bf(f0[i] * SCALE);
                u[i + 4] = f2bf(f1[i] * SCALE);
            }
            aq[c] = __builtin_bit_cast(bf16x8, u);
        }
    }

    const unsigned short* kbg = wk  + (size_t)b * NTILE * TILE_USH;
    const unsigned short* vbg = wvt + (size_t)b * NTILE * TILE_USH;

    // staging roles within a group: w4>>1 = K/V half, w4&1 = 8KB sub-slice
    const int s_half = w4 >> 1;
    const int s_sub  = w4 & 1;
    const unsigned short* sbase = s_half ? vbg : kbg;
    unsigned short* sdst = &smem[grp][s_half * 8192 + s_sub * 4096];
    const int s_off = s_sub * 4096 + lane * 8;

    float m_r = -1e30f;    // finite sentinel: empty groups merge NaN-free
    float l_r = 0.f;
    f32x16 accO[4];
    #pragma unroll
    for (int dc = 0; dc < 4; ++dc)
        #pragma unroll
        for (int r = 0; r < 16; ++r) accO[dc][r] = 0.f;

    // ---- prologue: group g stages tile g (8 x 1KB DMA per wave)
    if (grp < ntiles) {
        const unsigned short* src = sbase + (size_t)grp * TILE_USH + s_off;
        #pragma unroll
        for (int j = 0; j < 8; ++j) load_lds16(src + j * 512, sdst + j * 512);
    }
    __syncthreads();

    for (int i = 0; i < niter; ++i) {
        const int tile = 4 * i + grp;
        const unsigned short* kl  = &smem[grp][0];
        const unsigned short* vl2 = &smem[grp][8192];
        const bool act = (i < ng);

        us8 kf[16], vf[16];
        f32x16 sA, sB;
        if (act) {
            // ---- K frags -> regs, QK^T (swapped: S^T[64k x 32q])
            #pragma unroll
            for (int c = 0; c < 16; ++c)
                kf[c] = *(const us8*)&kl[c * 512 + lane * 8];
            #pragma unroll
            for (int r = 0; r < 16; ++r) { sA[r] = 0.f; sB[r] = 0.f; }
            __builtin_amdgcn_s_setprio(1);
            #pragma unroll
            for (int c = 0; c < 8; ++c) {
                sA = __builtin_amdgcn_mfma_f32_32x32x16_bf16(
                    __builtin_bit_cast(bf16x8, kf[c]), aq[c], sA, 0, 0, 0);
                sB = __builtin_amdgcn_mfma_f32_32x32x16_bf16(
                    __builtin_bit_cast(bf16x8, kf[8 + c]), aq[c], sB, 0, 0, 0);
            }
            __builtin_amdgcn_s_setprio(0);
            __builtin_amdgcn_sched_barrier(0);   // VGPR peak control
            // ---- V frags -> regs
            #pragma unroll
            for (int f = 0; f < 16; ++f)
                vf[f] = *(const us8*)&vl2[f * 512 + lane * 8];
        }

        // BARRIER A: all ds_reads drained (implicit lgkmcnt(0)) -> buffer free
        __syncthreads();

        // ---- issue next tile's DMA into the (now free) buffer
        {
            const int tn = 4 * (i + 1) + grp;
            if (tn < ntiles) {
                const unsigned short* src = sbase + (size_t)tn * TILE_USH + s_off;
                #pragma unroll
                for (int j = 0; j < 8; ++j) load_lds16(src + j * 512, sdst + j * 512);
            }
        }

        if (act) {
            const int kv0 = tile * KVBLK;

            // ---- mask (rows = k)
            if (uniform) {
                #pragma unroll
                for (int r = 0; r < 16; ++r) { sA[r] = 0.f; sB[r] = 0.f; }
            } else {
                const int lim0 = L - kv0 - 4 * hi;
                const int lim1 = lim0 - 32;
                #pragma unroll
                for (int r = 0; r < 16; ++r) {
                    const int rc = (r & 3) + 8 * (r >> 2);
                    sA[r] = (rc >= lim0) ? -__builtin_inff() : sA[r];
                    sB[r] = (rc >= lim1) ? -__builtin_inff() : sB[r];
                }
            }

            // ---- in-register softmax for q = lq
            float mx[8];
            #pragma unroll
            for (int i2 = 0; i2 < 8; ++i2)
                mx[i2] = fmaxf(fmaxf(sA[i2], sA[i2 + 8]), fmaxf(sB[i2], sB[i2 + 8]));
            #pragma unroll
            for (int i2 = 0; i2 < 4; ++i2) mx[i2] = fmaxf(mx[i2], mx[i2 + 4]);
            float pm = fmaxf(fmaxf(mx[0], mx[1]), fmaxf(mx[2], mx[3]));
            float pmax = fmaxf(pm, __shfl_xor(pm, 32));

            // T13: rescale only when some q-row got a new max
            if (__any(pmax > m_r)) {
                const float mnew = fmaxf(m_r, pmax);
                const float sc = __expf(m_r - mnew);
                m_r = mnew;
                l_r *= sc;
                #pragma unroll
                for (int r = 0; r < 16; ++r) {
                    const int src = ((r & 3) + 8 * (r >> 2) + 4 * hi) + (lane & 32);
                    const float scr = __shfl(sc, src);
                    accO[0][r] *= scr; accO[1][r] *= scr;
                    accO[2][r] *= scr; accO[3][r] *= scr;
                }
            }

            // ---- exp + row-sum
            float p0[16], p1[16];
            #pragma unroll
            for (int r = 0; r < 16; ++r) {
                p0[r] = __expf(sA[r] - m_r);
                p1[r] = __expf(sB[r] - m_r);
            }
            float sm[8];
            #pragma unroll
            for (int i2 = 0; i2 < 8; ++i2)
                sm[i2] = (p0[i2] + p0[i2 + 8]) + (p1[i2] + p1[i2 + 8]);
            #pragma unroll
            for (int i2 = 0; i2 < 4; ++i2) sm[i2] += sm[i2 + 4];
            float rsum = (sm[0] + sm[1]) + (sm[2] + sm[3]);
            rsum += __shfl_xor(rsum, 32);
            l_r += rsum;

            // ---- P -> bf16 packed words; half-exchange builds PV A-frags
            unsigned cw[16];
            #pragma unroll
            for (int i2 = 0; i2 < 8; ++i2) cw[i2] = cvt_pk_bf16(p0[2 * i2], p0[2 * i2 + 1]);
            #pragma unroll
            for (int i2 = 0; i2 < 8; ++i2) cw[8 + i2] = cvt_pk_bf16(p1[2 * i2], p1[2 * i2 + 1]);

            bf16x8 pa[4];
            #pragma unroll
            for (int ks = 0; ks < 4; ++ks) {
                const int a = 4 * ks;
                const unsigned u = hi ? cw[a]     : cw[a + 2];
                const unsigned v = hi ? cw[a + 1] : cw[a + 3];
                const unsigned up = __shfl_xor((int)u, 32);
                const unsigned vp = __shfl_xor((int)v, 32);
                u32x4 w;
                w[0] = hi ? up        : cw[a];
                w[1] = hi ? vp        : cw[a + 1];
                w[2] = hi ? cw[a + 2] : up;
                w[3] = hi ? cw[a + 3] : vp;
                pa[ks] = __builtin_bit_cast(bf16x8, w);
            }

            // ---- PV from regs
            __builtin_amdgcn_s_setprio(1);
            #pragma unroll
            for (int dc = 0; dc < 4; ++dc) {
                #pragma unroll
                for (int ks = 0; ks < 4; ++ks) {
                    accO[dc] = __builtin_amdgcn_mfma_f32_32x32x16_bf16(
                        pa[ks], __builtin_bit_cast(bf16x8, vf[ks * 4 + dc]), accO[dc], 0, 0, 0);
                }
            }
            __builtin_amdgcn_s_setprio(0);
        }

        // BARRIER B: implicit vmcnt(0) lands this iteration's DMA
        __syncthreads();
    }

    // ---- epilogue: groups 1-3 write bf16 partials + fp32 (m,l); group 0
    // tree-merges all three and stores normalized fp32 output.
    unsigned short* pbase = &smem[0][0];          // 3 x 32KB partial regions
    float* mlb = (float*)&smem[3][0];             // 3 x 256 floats
    if (grp >= 1) {
        unsigned short* pg = pbase + (size_t)(grp - 1) * 16384;
        #pragma unroll
        for (int dc = 0; dc < 4; ++dc) {
            #pragma unroll
            for (int q4 = 0; q4 < 4; ++q4) {
                us4 w;
                #pragma unroll
                for (int c = 0; c < 4; ++c) w[c] = f2bf(accO[dc][q4 * 4 + c]);
                *(us4*)&pg[(((w4 * 16 + dc * 4 + q4) * 64) + lane) * 4] = w;
            }
        }
        if (hi == 0) {
            mlb[(grp - 1) * 256 + w4 * 32 + lq]       = m_r;
            mlb[(grp - 1) * 256 + 128 + w4 * 32 + lq] = l_r;
        }
    }
    __syncthreads();
    if (grp == 0) {
        #pragma unroll
        for (int g = 1; g < 4; ++g) {
            const float mg = mlb[(g - 1) * 256 + w4 * 32 + lq];
            const float lg = mlb[(g - 1) * 256 + 128 + w4 * 32 + lq];
            const float mn = fmaxf(m_r, mg);
            const float a0 = __expf(m_r - mn);
            const float a1 = __expf(mg - mn);
            m_r = mn;
            l_r = a0 * l_r + a1 * lg;
            // per-row factors
            float a0v[16], a1v[16];
            #pragma unroll
            for (int r = 0; r < 16; ++r) {
                const int row = (r & 3) + 8 * (r >> 2) + 4 * hi;
                a0v[r] = __shfl(a0, row + (lane & 32));
                a1v[r] = __shfl(a1, row + (lane & 32));
            }
            const unsigned short* pg = pbase + (size_t)(g - 1) * 16384;
            #pragma unroll
            for (int dc = 0; dc < 4; ++dc) {
                #pragma unroll
                for (int q4 = 0; q4 < 4; ++q4) {
                    us4 w = *(const us4*)&pg[(((w4 * 16 + dc * 4 + q4) * 64) + lane) * 4];
                    #pragma unroll
                    for (int c = 0; c < 4; ++c) {
                        const int r = q4 * 4 + c;
                        accO[dc][r] = accO[dc][r] * a0v[r] + bf2f(w[c]) * a1v[r];
                    }
                }
            }
        }
        // normalize + store
        const float inv = 1.0f / l_r;
        float invv[16];
        #pragma unroll
        for (int r = 0; r < 16; ++r) {
            const int row = (r & 3) + 8 * (r >> 2) + 4 * hi;
            invv[r] = __shfl(inv, row + (lane & 32));
        }
        float* ob = og + (size_t)(b * NQ + q0 + w4 * 32) * ND;
        #pragma unroll
        for (int dc = 0; dc < 4; ++dc) {
            #pragma unroll
            for (int r = 0; r < 16; ++r) {
                const int row = (r & 3) + 8 * (r >> 2) + 4 * hi;
                ob[(size_t)row * ND + dc * 32 + lq] = accO[dc][r] * invv[r];
            }
        }
    }
}

// ---------------------------------------------------------------------------
// Fallback (R1 kernel): used only if ws_size < 16 MB
// ---------------------------------------------------------------------------
__global__ __launch_bounds__(256, 2)
void attn_fused(const float* __restrict__ qg, const float* __restrict__ kg,
                const float* __restrict__ vg, const int* __restrict__ vlen,
                float* __restrict__ og)
{
    const int b    = blockIdx.y;
    const int q0   = blockIdx.x * 64;
    const int tid  = threadIdx.x;
    const int wid  = tid >> 6;
    const int lane = tid & 63;
    const int lrow = lane & 15;
    const int lgrp = lane >> 4;

    const int L = vlen[b];
    const bool uniform = (L <= 0);
    const int Leff = uniform ? NK : L;
    const int nt32 = (Leff + 31) / 32;

    __shared__ __align__(16) unsigned short kt[32 * 136];
    __shared__ __align__(16) unsigned short vt[128 * 40];
    __shared__ __align__(16) float pt[4][16 * 36];

    bf16x8 aqf[4];
    {
        const float* qp = qg + (size_t)(b * NQ + q0 + wid * 16 + lrow) * ND + lgrp * 8;
        #pragma unroll
        for (int c = 0; c < 4; ++c) {
            f4 f0 = *(const f4*)(qp + c * 32);
            f4 f1 = *(const f4*)(qp + c * 32 + 4);
            us8 u;
            #pragma unroll
            for (int i = 0; i < 4; ++i) {
                u[i]     = f2bf(f0[i] * SCALE);
                u[i + 4] = f2bf(f1[i] * SCALE);
            }
            aqf[c] = __builtin_bit_cast(bf16x8, u);
        }
    }

    float m_r[4], l_r[4];
    f4 accO[8];
    #pragma unroll
    for (int r = 0; r < 4; ++r) { m_r[r] = -__builtin_inff(); l_r[r] = 0.f; }
    #pragma unroll
    for (int dc = 0; dc < 8; ++dc) accO[dc] = splat4(0.f);

    for (int t = 0; t < nt32; ++t) {
        const int kv0 = t * 32;
        __syncthreads();
        {
            const int r  = tid >> 3;
            const int c0 = (tid & 7) * 16;
            const float* gp = kg + (size_t)(b * NK + kv0 + r) * ND + c0;
            f4 f0 = *(const f4*)(gp);
            f4 f1 = *(const f4*)(gp + 4);
            f4 f2 = *(const f4*)(gp + 8);
            f4 f3 = *(const f4*)(gp + 12);
            us8 w0, w1;
            #pragma unroll
            for (int i = 0; i < 4; ++i) {
                w0[i]     = f2bf(f0[i]);
                w0[i + 4] = f2bf(f1[i]);
                w1[i]     = f2bf(f2[i]);
                w1[i + 4] = f2bf(f3[i]);
            }
            unsigned short* dst = &kt[r * 136 + c0];
            *(us8*)(dst)     = w0;
            *(us8*)(dst + 8) = w1;
        }
        {
            const int d  = tid & 127;
            const int g2 = tid >> 7;
            const float* gp = vg + (size_t)(b * NK + kv0 + g2 * 16) * ND + d;
            us8 w0, w1;
            #pragma unroll
            for (int j = 0; j < 8; ++j) {
                w0[j] = f2bf(gp[(size_t)j * ND]);
                w1[j] = f2bf(gp[(size_t)(j + 8) * ND]);
            }
            unsigned short* dst = &vt[d * 40 + g2 * 16];
            *(us8*)(dst)     = w0;
            *(us8*)(dst + 8) = w1;
        }
        __syncthreads();

        f4 s0 = splat4(0.f), s1 = splat4(0.f);
        #pragma unroll
        for (int c = 0; c < 4; ++c) {
            bf16x8 bk0 = __builtin_bit_cast(bf16x8,
                *(const us8*)&kt[lrow * 136 + c * 32 + lgrp * 8]);
            s0 = __builtin_amdgcn_mfma_f32_16x16x32_bf16(aqf[c], bk0, s0, 0, 0, 0);
            bf16x8 bk1 = __builtin_bit_cast(bf16x8,
                *(const us8*)&kt[(16 + lrow) * 136 + c * 32 + lgrp * 8]);
            s1 = __builtin_amdgcn_mfma_f32_16x16x32_bf16(aqf[c], bk1, s1, 0, 0, 0);
        }

        const int col0 = kv0 + lrow;
        if (uniform) {
            s0 = splat4(0.f);
            s1 = splat4(0.f);
        } else {
            if (col0 >= L)      s0 = splat4(-__builtin_inff());
            if (col0 + 16 >= L) s1 = splat4(-__builtin_inff());
        }

        float pm[4];
        #pragma unroll
        for (int r = 0; r < 4; ++r) pm[r] = fmaxf(s0[r], s1[r]);
        #pragma unroll
        for (int off = 8; off > 0; off >>= 1) {
            #pragma unroll
            for (int r = 0; r < 4; ++r)
                pm[r] = fmaxf(pm[r], __shfl_xor(pm[r], off));
        }
        float pr0[4], pr1[4], rs[4], sc[4];
        #pragma unroll
        for (int r = 0; r < 4; ++r) {
            float mn = fmaxf(m_r[r], pm[r]);
            sc[r]  = __expf(m_r[r] - mn);
            m_r[r] = mn;
            pr0[r] = __expf(s0[r] - mn);
            pr1[r] = __expf(s1[r] - mn);
            rs[r]  = pr0[r] + pr1[r];
        }
        #pragma unroll
        for (int off = 8; off > 0; off >>= 1) {
            #pragma unroll
            for (int r = 0; r < 4; ++r)
                rs[r] += __shfl_xor(rs[r], off);
        }
        #pragma unroll
        for (int r = 0; r < 4; ++r) l_r[r] = l_r[r] * sc[r] + rs[r];
        #pragma unroll
        for (int dc = 0; dc < 8; ++dc) {
            #pragma unroll
            for (int r = 0; r < 4; ++r) accO[dc][r] *= sc[r];
        }

        float* pw = pt[wid];
        #pragma unroll
        for (int r = 0; r < 4; ++r) {
            pw[(lgrp * 4 + r) * 36 + lrow]      = pr0[r];
            pw[(lgrp * 4 + r) * 36 + 16 + lrow] = pr1[r];
        }
        asm volatile("s_waitcnt lgkmcnt(0)" ::: "memory");
        f4 a0 = *(const f4*)&pw[lrow * 36 + lgrp * 8];
        f4 a1 = *(const f4*)&pw[lrow * 36 + lgrp * 8 + 4];
        us8 au;
        #pragma unroll
        for (int i = 0; i < 4; ++i) { au[i] = f2bf(a0[i]); au[i + 4] = f2bf(a1[i]); }
        bf16x8 ap = __builtin_bit_cast(bf16x8, au);

        #pragma unroll
        for (int dc = 0; dc < 8; ++dc) {
            bf16x8 bv = __builtin_bit_cast(bf16x8,
                *(const us8*)&vt[(dc * 16 + lrow) * 40 + lgrp * 8]);
            accO[dc] = __builtin_amdgcn_mfma_f32_16x16x32_bf16(ap, bv, accO[dc], 0, 0, 0);
        }
    }

    float inv[4];
    #pragma unroll
    for (int r = 0; r < 4; ++r) inv[r] = 1.0f / l_r[r];
    float* op = og + (size_t)(b * NQ + q0 + wid * 16) * ND;
    #pragma unroll
    for (int dc = 0; dc < 8; ++dc) {
        #pragma unroll
        for (int r = 0; r < 4; ++r)
            op[(lgrp * 4 + r) * ND + dc * 16 + lrow] = accO[dc][r] * inv[r];
    }
}

extern "C" void kernel_launch(void* const* d_in, const int* in_sizes, int n_in,
                              void* d_out, int out_size, void* d_ws, size_t ws_size,
                              hipStream_t stream) {
    (void)in_sizes; (void)n_in; (void)out_size;
    const float* q  = (const float*)d_in[0];
    const float* k  = (const float*)d_in[1];
    const float* v  = (const float*)d_in[2];
    const int*   vl = (const int*)d_in[3];
    float* out = (float*)d_out;

    const size_t kvbytes = 2 * (size_t)NB * NK * ND * sizeof(unsigned short); // 16 MB
    if (ws_size >= kvbytes) {
        unsigned short* wk  = (unsigned short*)d_ws;
        unsigned short* wvt = wk + (size_t)NB * NK * ND;
        hipLaunchKernelGGL(prep_kv4, dim3(NTILE, NB), dim3(256), 0, stream, k, v, wk, wvt);
        hipLaunchKernelGGL(attn_fused12, dim3((NQ / 128) * NB), dim3(1024), 0, stream,
                           q, vl, wk, wvt, out);
    } else {
        hipLaunchKernelGGL(attn_fused, dim3(NQ / 64, NB), dim3(256), 0, stream,
                           q, k, v, vl, out);
    }
}

// Round 13
// 131.388 us; speedup vs baseline: 3.9025x; 3.9025x over previous
//
#include <hip/hip_runtime.h>

// Problem constants (reference: B=16, Q=2048, K=2048, D=128, fp32, NEG=-1e6)
constexpr int NB = 16;
constexpr int NQ = 2048;
constexpr int NK = 2048;
constexpr int ND = 128;
constexpr int KVBLK = 64;                 // kv per tile
constexpr int NTILE = NK / KVBLK;         // 32
constexpr int TILE_USH = KVBLK * ND;      // 8192 ushorts = 16KB per tile
constexpr float SCALE = 0.08838834764831844f; // 1/sqrt(128)

typedef __attribute__((ext_vector_type(4))) float f4;
typedef __attribute__((ext_vector_type(16))) float f32x16;
typedef __attribute__((ext_vector_type(8))) unsigned short us8;
typedef __attribute__((ext_vector_type(8))) __bf16 bf16x8;
typedef __attribute__((ext_vector_type(4))) unsigned int u32x4;

static __device__ __forceinline__ unsigned short f2bf(float f) {
    unsigned u = __builtin_bit_cast(unsigned, f);
    u += 0x7fffu + ((u >> 16) & 1u);
    return (unsigned short)(u >> 16);
}
static __device__ __forceinline__ f4 splat4(float x) { f4 r = {x,x,x,x}; return r; }

static __device__ __forceinline__ void load_lds16(const unsigned short* g, unsigned short* l) {
    __builtin_amdgcn_global_load_lds(
        (const __attribute__((address_space(1))) void*)g,
        (__attribute__((address_space(3))) void*)l,
        16, 0, 0);
}

static __device__ __forceinline__ unsigned cvt_pk_bf16(float lo, float hi) {
    unsigned r;
    asm("v_cvt_pk_bf16_f32 %0, %1, %2" : "=v"(r) : "v"(lo), "v"(hi));
    return r;
}

// ---------------------------------------------------------------------------
// Prep: per (batch, kv-tile=64) write K and V in lane-linear 32x32-MFMA
// fragment order (verified R5-R12):
//  K  (kv,d): off = ((kv>>5)*8 + (d>>4))*512 + ((d>>3)&1)*256 + (kv&31)*8 + (d&7)
//  V  (kv,d): off = ((kv>>4)*4 + (d>>5))*512 + ((kv>>3)&1)*256 + (d&31)*8 + (kv&7)
// grid (NTILE, NB), 256 threads
// ---------------------------------------------------------------------------
__global__ __launch_bounds__(256)
void prep_kv4(const float* __restrict__ kg, const float* __restrict__ vg,
              unsigned short* __restrict__ wk, unsigned short* __restrict__ wvt)
{
    const int b   = blockIdx.y;
    const int t   = blockIdx.x;
    const int kv0 = t * KVBLK;
    const int t0  = threadIdx.x;

    __shared__ __align__(16) unsigned short vl[64 * 136];

    {
        const int kv = t0 >> 2;
        const int c  = t0 & 3;
        const float* gp = kg + (size_t)(b * NK + kv0 + kv) * ND + c * 32;
        unsigned short* ob = wk + (size_t)(b * NTILE + t) * TILE_USH;
        #pragma unroll
        for (int g = 0; g < 4; ++g) {
            f4 f0 = *(const f4*)(gp + g * 8);
            f4 f1 = *(const f4*)(gp + g * 8 + 4);
            us8 w;
            #pragma unroll
            for (int i = 0; i < 4; ++i) { w[i] = f2bf(f0[i]); w[i+4] = f2bf(f1[i]); }
            const int d0 = c * 32 + g * 8;
            const int f  = (kv >> 5) * 8 + (d0 >> 4);
            const int off = f * 512 + ((d0 >> 3) & 1) * 256 + (kv & 31) * 8;
            *(us8*)(ob + off) = w;
        }
    }
    {
        const int kv = t0 >> 2;
        const int d0 = (t0 & 3) * 32;
        const float* gp = vg + (size_t)(b * NK + kv0 + kv) * ND + d0;
        unsigned short* lb = &vl[kv * 136 + d0];
        #pragma unroll
        for (int g = 0; g < 4; ++g) {
            f4 f0 = *(const f4*)(gp + g * 8);
            f4 f1 = *(const f4*)(gp + g * 8 + 4);
            us8 w;
            #pragma unroll
            for (int i = 0; i < 4; ++i) { w[i] = f2bf(f0[i]); w[i+4] = f2bf(f1[i]); }
            *(us8*)(lb + g * 8) = w;
        }
    }
    __syncthreads();
    {
        unsigned short* ob = wvt + (size_t)(b * NTILE + t) * TILE_USH;
        #pragma unroll
        for (int iter = 0; iter < 4; ++iter) {
            const int cid = iter * 256 + t0;
            const int f   = cid >> 6;
            const int l   = cid & 63;
            const int kb  = (f >> 2) * 16 + (l >> 5) * 8;
            const int d   = (f & 3) * 32 + (l & 31);
            us8 w;
            #pragma unroll
            for (int j = 0; j < 8; ++j) w[j] = vl[(kb + j) * 136 + d];
            *(us8*)(ob + cid * 8) = w;
        }
    }
}

// ---- per-tile phases as macros (no lambdas: avoids R10's regalloc blowup)
#define QK_STREAM(KL, SA, SB) do {                                             \
    _Pragma("unroll")                                                          \
    for (int r_ = 0; r_ < 16; ++r_) { (SA)[r_] = 0.f; (SB)[r_] = 0.f; }        \
    __builtin_amdgcn_s_setprio(1);                                             \
    _Pragma("unroll")                                                          \
    for (int c_ = 0; c_ < 8; ++c_) {                                           \
        us8 k0_ = *(const us8*)&(KL)[c_ * 512 + lane * 8];                     \
        (SA) = __builtin_amdgcn_mfma_f32_32x32x16_bf16(                        \
            __builtin_bit_cast(bf16x8, k0_), aq[c_], (SA), 0, 0, 0);           \
        us8 k1_ = *(const us8*)&(KL)[(8 + c_) * 512 + lane * 8];               \
        (SB) = __builtin_amdgcn_mfma_f32_32x32x16_bf16(                        \
            __builtin_bit_cast(bf16x8, k1_), aq[c_], (SB), 0, 0, 0);           \
    }                                                                          \
    __builtin_amdgcn_s_setprio(0);                                             \
} while (0)

#define LOADV(VL, VF) do {                                                     \
    _Pragma("unroll")                                                          \
    for (int f_ = 0; f_ < 16; ++f_)                                            \
        (VF)[f_] = *(const us8*)&(VL)[f_ * 512 + lane * 8];                    \
} while (0)

#define FINISH(SA, SB, VF, KV0) do {                                           \
    if (uniform) {                                                             \
        _Pragma("unroll")                                                      \
        for (int r_ = 0; r_ < 16; ++r_) { (SA)[r_] = 0.f; (SB)[r_] = 0.f; }    \
    } else {                                                                   \
        const int lim0_ = L - (KV0) - 4 * hi;                                  \
        const int lim1_ = lim0_ - 32;                                          \
        _Pragma("unroll")                                                      \
        for (int r_ = 0; r_ < 16; ++r_) {                                      \
            const int rc_ = (r_ & 3) + 8 * (r_ >> 2);                          \
            (SA)[r_] = (rc_ >= lim0_) ? -__builtin_inff() : (SA)[r_];          \
            (SB)[r_] = (rc_ >= lim1_) ? -__builtin_inff() : (SB)[r_];          \
        }                                                                      \
    }                                                                          \
    float mx_[8];                                                              \
    _Pragma("unroll")                                                          \
    for (int i_ = 0; i_ < 8; ++i_)                                             \
        mx_[i_] = fmaxf(fmaxf((SA)[i_], (SA)[i_ + 8]),                         \
                        fmaxf((SB)[i_], (SB)[i_ + 8]));                        \
    _Pragma("unroll")                                                          \
    for (int i_ = 0; i_ < 4; ++i_) mx_[i_] = fmaxf(mx_[i_], mx_[i_ + 4]);      \
    float pm_ = fmaxf(fmaxf(mx_[0], mx_[1]), fmaxf(mx_[2], mx_[3]));           \
    float pmax_ = fmaxf(pm_, __shfl_xor(pm_, 32));                             \
    if (__any(pmax_ > m_r)) {                                                  \
        const float mnew_ = fmaxf(m_r, pmax_);                                 \
        const float sc_ = __expf(m_r - mnew_);                                 \
        m_r = mnew_;                                                           \
        l_r *= sc_;                                                            \
        _Pragma("unroll")                                                      \
        for (int r_ = 0; r_ < 16; ++r_) {                                      \
            const int src_ = ((r_ & 3) + 8 * (r_ >> 2) + 4 * hi) + (lane & 32);\
            const float scr_ = __shfl(sc_, src_);                              \
            accO[0][r_] *= scr_; accO[1][r_] *= scr_;                          \
            accO[2][r_] *= scr_; accO[3][r_] *= scr_;                          \
        }                                                                      \
    }                                                                          \
    float p0_[16], p1_[16];                                                    \
    _Pragma("unroll")                                                          \
    for (int r_ = 0; r_ < 16; ++r_) {                                          \
        p0_[r_] = __expf((SA)[r_] - m_r);                                      \
        p1_[r_] = __expf((SB)[r_] - m_r);                                      \
    }                                                                          \
    float sm_[8];                                                              \
    _Pragma("unroll")                                                          \
    for (int i_ = 0; i_ < 8; ++i_)                                             \
        sm_[i_] = (p0_[i_] + p0_[i_ + 8]) + (p1_[i_] + p1_[i_ + 8]);           \
    _Pragma("unroll")                                                          \
    for (int i_ = 0; i_ < 4; ++i_) sm_[i_] += sm_[i_ + 4];                     \
    float rsum_ = (sm_[0] + sm_[1]) + (sm_[2] + sm_[3]);                       \
    rsum_ += __shfl_xor(rsum_, 32);                                            \
    l_r += rsum_;                                                              \
    unsigned cw_[16];                                                          \
    _Pragma("unroll")                                                          \
    for (int i_ = 0; i_ < 8; ++i_)                                             \
        cw_[i_] = cvt_pk_bf16(p0_[2 * i_], p0_[2 * i_ + 1]);                   \
    _Pragma("unroll")                                                          \
    for (int i_ = 0; i_ < 8; ++i_)                                             \
        cw_[8 + i_] = cvt_pk_bf16(p1_[2 * i_], p1_[2 * i_ + 1]);               \
    bf16x8 pa_[4];                                                             \
    _Pragma("unroll")                                                          \
    for (int ks_ = 0; ks_ < 4; ++ks_) {                                        \
        const int a_ = 4 * ks_;                                                \
        const unsigned u_ = hi ? cw_[a_]     : cw_[a_ + 2];                    \
        const unsigned v_ = hi ? cw_[a_ + 1] : cw_[a_ + 3];                    \
        const unsigned up_ = __shfl_xor((int)u_, 32);                          \
        const unsigned vp_ = __shfl_xor((int)v_, 32);                          \
        u32x4 w_;                                                              \
        w_[0] = hi ? up_        : cw_[a_];                                     \
        w_[1] = hi ? vp_        : cw_[a_ + 1];                                 \
        w_[2] = hi ? cw_[a_ + 2] : up_;                                        \
        w_[3] = hi ? cw_[a_ + 3] : vp_;                                        \
        pa_[ks_] = __builtin_bit_cast(bf16x8, w_);                             \
    }                                                                          \
    __builtin_amdgcn_s_setprio(1);                                             \
    _Pragma("unroll")                                                          \
    for (int dc_ = 0; dc_ < 4; ++dc_) {                                        \
        _Pragma("unroll")                                                      \
        for (int ks_ = 0; ks_ < 4; ++ks_) {                                    \
            accO[dc_] = __builtin_amdgcn_mfma_f32_32x32x16_bf16(               \
                pa_[ks_], __builtin_bit_cast(bf16x8, (VF)[ks_ * 4 + dc_]),     \
                accO[dc_], 0, 0, 0);                                           \
        }                                                                      \
    }                                                                          \
    __builtin_amdgcn_s_setprio(0);                                             \
} while (0)

// ---------------------------------------------------------------------------
// Fused attention v13: R7 shape (512 thr, 2 KV-groups x 4 q-waves, QBLK=128,
// grid=256, XCD batch affinity) with TWO tiles per barrier-pair in a 64KB
// per-group buffer [K0|V0|K1|V1]. kf streamed (no array). Tile1's SM+PV runs
// after barrier A, covering the next pair's DMA. Iterations halve vs R11.
// ---------------------------------------------------------------------------
__global__ __launch_bounds__(512, 2)
void attn_fused13(const float* __restrict__ qg, const int* __restrict__ vlen,
                  const unsigned short* __restrict__ wk,
                  const unsigned short* __restrict__ wvt,
                  float* __restrict__ og)
{
    const int bid = blockIdx.x;
    const int b   = bid & 15;      // XCD x hosts batches {x, x+8}: KV L2-resident
    const int qc  = bid >> 4;
    const int q0  = qc * 128;

    const int tid  = threadIdx.x;
    const int wid  = tid >> 6;
    const int grp  = wid >> 2;     // KV group 0/1
    const int w4   = wid & 3;      // q-wave within group (32 rows each)
    const int lane = tid & 63;
    const int lq   = lane & 31;
    const int hi   = lane >> 5;

    const int L = vlen[b];
    const bool uniform = (L <= 0);
    const int Leff = uniform ? NK : L;
    const int ntiles = (Leff + KVBLK - 1) / KVBLK;
    const int niter  = (ntiles + 3) >> 2;    // pairs per group (group0 bound)

    // per-group 64KB buffer: [K0 16K | V0 16K | K1 16K | V1 16K]; 128KB total
    __shared__ __align__(16) unsigned short smem[2][4 * TILE_USH];

    // ---- Q fragments (B-operand), scaled
    bf16x8 aq[8];
    {
        const float* qp = qg + (size_t)(b * NQ + q0 + w4 * 32 + lq) * ND + hi * 8;
        #pragma unroll
        for (int c = 0; c < 8; ++c) {
            f4 f0 = *(const f4*)(qp + c * 16);
            f4 f1 = *(const f4*)(qp + c * 16 + 4);
            us8 u;
            #pragma unroll
            for (int i = 0; i < 4; ++i) {
                u[i]     = f2bf(f0[i] * SCALE);
                u[i + 4] = f2bf(f1[i] * SCALE);
            }
            aq[c] = __builtin_bit_cast(bf16x8, u);
        }
    }

    const unsigned short* kbg = wk  + (size_t)b * NTILE * TILE_USH;
    const unsigned short* vbg = wvt + (size_t)b * NTILE * TILE_USH;

    // staging: wave w4 of group grp stages segment w4 = {K(t+0),V(t+0),K(t+1),V(t+1)}
    const unsigned short* sbase = (w4 & 1) ? vbg : kbg;
    const int s_tile = w4 >> 1;                  // tile-of-pair this wave stages
    unsigned short* sdst = &smem[grp][w4 * 8192];

    float m_r = -__builtin_inff();
    float l_r = 0.f;
    f32x16 accO[4];
    #pragma unroll
    for (int dc = 0; dc < 4; ++dc)
        #pragma unroll
        for (int r = 0; r < 16; ++r) accO[dc][r] = 0.f;

    // ---- prologue: stage pair 0 (tiles 2g, 2g+1)
    {
        const int tn = 2 * grp + s_tile;
        if (tn < ntiles) {
            const unsigned short* src = sbase + (size_t)tn * TILE_USH + lane * 8;
            #pragma unroll
            for (int j = 0; j < 16; ++j) load_lds16(src + j * 512, sdst + j * 512);
        }
    }
    __syncthreads();

    for (int i = 0; i < niter; ++i) {
        const int t0 = 4 * i + 2 * grp;
        const int t1 = t0 + 1;
        const bool a0 = (t0 < ntiles);
        const bool a1 = (t1 < ntiles);
        const unsigned short* base = &smem[grp][0];

        // ---- tile0: full pipeline (QK streamed from LDS, SM+PV)
        if (a0) {
            f32x16 s0A, s0B;
            us8 vf0[16];
            QK_STREAM(base, s0A, s0B);
            __builtin_amdgcn_sched_barrier(0);
            LOADV(base + 8192, vf0);
            FINISH(s0A, s0B, vf0, t0 * KVBLK);
        }

        // ---- tile1: QK + V loads before the barrier; SM+PV after
        f32x16 s1A, s1B;
        us8 vf1[16];
        if (a1) {
            QK_STREAM(base + 16384, s1A, s1B);
            __builtin_amdgcn_sched_barrier(0);
            LOADV(base + 24576, vf1);
        }

        // BARRIER A: all LDS reads drained -> buffer free for next pair's DMA
        __syncthreads();

        {
            const int tn = 4 * (i + 1) + 2 * grp + s_tile;
            if (tn < ntiles) {
                const unsigned short* src = sbase + (size_t)tn * TILE_USH + lane * 8;
                #pragma unroll
                for (int j = 0; j < 16; ++j) load_lds16(src + j * 512, sdst + j * 512);
            }
        }

        // tile1's SM+PV covers the DMA flight
        if (a1) FINISH(s1A, s1B, vf1, t1 * KVBLK);

        // BARRIER B: implicit vmcnt(0) lands this iteration's DMA
        __syncthreads();
    }

    // ---- merge epilogue: group1 -> LDS (fp32 accO + m/l), group0 combines
    float* accb = (float*)&smem[0][0];     // 64 KB region
    float* mlb  = (float*)&smem[1][0];     // m[128], l[128]
    if (grp == 1) {
        #pragma unroll
        for (int dc = 0; dc < 4; ++dc) {
            #pragma unroll
            for (int q4 = 0; q4 < 4; ++q4) {
                f4 v;
                #pragma unroll
                for (int c = 0; c < 4; ++c) v[c] = accO[dc][q4 * 4 + c];
                *(f4*)&accb[(((w4 * 16 + dc * 4 + q4) * 64) + lane) * 4] = v;
            }
        }
        if (hi == 0) {
            mlb[w4 * 32 + lq]       = m_r;
            mlb[128 + w4 * 32 + lq] = l_r;
        }
    }
    __syncthreads();
    if (grp == 0) {
        const float m1 = mlb[w4 * 32 + lq];
        const float l1 = mlb[128 + w4 * 32 + lq];
        const float m  = fmaxf(m_r, m1);
        const float a0 = __expf(m_r - m), a1 = __expf(m1 - m);
        const float linv = 1.0f / (a0 * l_r + a1 * l1);
        const float s0v = a0 * linv, s1v = a1 * linv;
        float* ob = og + (size_t)(b * NQ + q0 + w4 * 32) * ND;
        #pragma unroll
        for (int dc = 0; dc < 4; ++dc) {
            #pragma unroll
            for (int q4 = 0; q4 < 4; ++q4) {
                f4 o1 = *(const f4*)&accb[(((w4 * 16 + dc * 4 + q4) * 64) + lane) * 4];
                #pragma unroll
                for (int c = 0; c < 4; ++c) {
                    const int r = q4 * 4 + c;
                    const int row = c + 8 * q4 + 4 * hi;
                    const float s0r = __shfl(s0v, row + (lane & 32));
                    const float s1r = __shfl(s1v, row + (lane & 32));
                    ob[(size_t)row * ND + dc * 32 + lq] = accO[dc][r] * s0r + o1[c] * s1r;
                }
            }
        }
    }
}

// ---------------------------------------------------------------------------
// Fallback (R1 kernel): used only if ws_size < 16 MB
// ---------------------------------------------------------------------------
__global__ __launch_bounds__(256, 2)
void attn_fused(const float* __restrict__ qg, const float* __restrict__ kg,
                const float* __restrict__ vg, const int* __restrict__ vlen,
                float* __restrict__ og)
{
    const int b    = blockIdx.y;
    const int q0   = blockIdx.x * 64;
    const int tid  = threadIdx.x;
    const int wid  = tid >> 6;
    const int lane = tid & 63;
    const int lrow = lane & 15;
    const int lgrp = lane >> 4;

    const int L = vlen[b];
    const bool uniform = (L <= 0);
    const int Leff = uniform ? NK : L;
    const int nt32 = (Leff + 31) / 32;

    __shared__ __align__(16) unsigned short kt[32 * 136];
    __shared__ __align__(16) unsigned short vt[128 * 40];
    __shared__ __align__(16) float pt[4][16 * 36];

    bf16x8 aqf[4];
    {
        const float* qp = qg + (size_t)(b * NQ + q0 + wid * 16 + lrow) * ND + lgrp * 8;
        #pragma unroll
        for (int c = 0; c < 4; ++c) {
            f4 f0 = *(const f4*)(qp + c * 32);
            f4 f1 = *(const f4*)(qp + c * 32 + 4);
            us8 u;
            #pragma unroll
            for (int i = 0; i < 4; ++i) {
                u[i]     = f2bf(f0[i] * SCALE);
                u[i + 4] = f2bf(f1[i] * SCALE);
            }
            aqf[c] = __builtin_bit_cast(bf16x8, u);
        }
    }

    float m_r[4], l_r[4];
    f4 accO[8];
    #pragma unroll
    for (int r = 0; r < 4; ++r) { m_r[r] = -__builtin_inff(); l_r[r] = 0.f; }
    #pragma unroll
    for (int dc = 0; dc < 8; ++dc) accO[dc] = splat4(0.f);

    for (int t = 0; t < nt32; ++t) {
        const int kv0 = t * 32;
        __syncthreads();
        {
            const int r  = tid >> 3;
            const int c0 = (tid & 7) * 16;
            const float* gp = kg + (size_t)(b * NK + kv0 + r) * ND + c0;
            f4 f0 = *(const f4*)(gp);
            f4 f1 = *(const f4*)(gp + 4);
            f4 f2 = *(const f4*)(gp + 8);
            f4 f3 = *(const f4*)(gp + 12);
            us8 w0, w1;
            #pragma unroll
            for (int i = 0; i < 4; ++i) {
                w0[i]     = f2bf(f0[i]);
                w0[i + 4] = f2bf(f1[i]);
                w1[i]     = f2bf(f2[i]);
                w1[i + 4] = f2bf(f3[i]);
            }
            unsigned short* dst = &kt[r * 136 + c0];
            *(us8*)(dst)     = w0;
            *(us8*)(dst + 8) = w1;
        }
        {
            const int d  = tid & 127;
            const int g2 = tid >> 7;
            const float* gp = vg + (size_t)(b * NK + kv0 + g2 * 16) * ND + d;
            us8 w0, w1;
            #pragma unroll
            for (int j = 0; j < 8; ++j) {
                w0[j] = f2bf(gp[(size_t)j * ND]);
                w1[j] = f2bf(gp[(size_t)(j + 8) * ND]);
            }
            unsigned short* dst = &vt[d * 40 + g2 * 16];
            *(us8*)(dst)     = w0;
            *(us8*)(dst + 8) = w1;
        }
        __syncthreads();

        f4 s0 = splat4(0.f), s1 = splat4(0.f);
        #pragma unroll
        for (int c = 0; c < 4; ++c) {
            bf16x8 bk0 = __builtin_bit_cast(bf16x8,
                *(const us8*)&kt[lrow * 136 + c * 32 + lgrp * 8]);
            s0 = __builtin_amdgcn_mfma_f32_16x16x32_bf16(aqf[c], bk0, s0, 0, 0, 0);
            bf16x8 bk1 = __builtin_bit_cast(bf16x8,
                *(const us8*)&kt[(16 + lrow) * 136 + c * 32 + lgrp * 8]);
            s1 = __builtin_amdgcn_mfma_f32_16x16x32_bf16(aqf[c], bk1, s1, 0, 0, 0);
        }

        const int col0 = kv0 + lrow;
        if (uniform) {
            s0 = splat4(0.f);
            s1 = splat4(0.f);
        } else {
            if (col0 >= L)      s0 = splat4(-__builtin_inff());
            if (col0 + 16 >= L) s1 = splat4(-__builtin_inff());
        }

        float pm[4];
        #pragma unroll
        for (int r = 0; r < 4; ++r) pm[r] = fmaxf(s0[r], s1[r]);
        #pragma unroll
        for (int off = 8; off > 0; off >>= 1) {
            #pragma unroll
            for (int r = 0; r < 4; ++r)
                pm[r] = fmaxf(pm[r], __shfl_xor(pm[r], off));
        }
        float pr0[4], pr1[4], rs[4], sc[4];
        #pragma unroll
        for (int r = 0; r < 4; ++r) {
            float mn = fmaxf(m_r[r], pm[r]);
            sc[r]  = __expf(m_r[r] - mn);
            m_r[r] = mn;
            pr0[r] = __expf(s0[r] - mn);
            pr1[r] = __expf(s1[r] - mn);
            rs[r]  = pr0[r] + pr1[r];
        }
        #pragma unroll
        for (int off = 8; off > 0; off >>= 1) {
            #pragma unroll
            for (int r = 0; r < 4; ++r)
                rs[r] += __shfl_xor(rs[r], off);
        }
        #pragma unroll
        for (int r = 0; r < 4; ++r) l_r[r] = l_r[r] * sc[r] + rs[r];
        #pragma unroll
        for (int dc = 0; dc < 8; ++dc) {
            #pragma unroll
            for (int r = 0; r < 4; ++r) accO[dc][r] *= sc[r];
        }

        float* pw = pt[wid];
        #pragma unroll
        for (int r = 0; r < 4; ++r) {
            pw[(lgrp * 4 + r) * 36 + lrow]      = pr0[r];
            pw[(lgrp * 4 + r) * 36 + 16 + lrow] = pr1[r];
        }
        asm volatile("s_waitcnt lgkmcnt(0)" ::: "memory");
        f4 a0 = *(const f4*)&pw[lrow * 36 + lgrp * 8];
        f4 a1 = *(const f4*)&pw[lrow * 36 + lgrp * 8 + 4];
        us8 au;
        #pragma unroll
        for (int i = 0; i < 4; ++i) { au[i] = f2bf(a0[i]); au[i + 4] = f2bf(a1[i]); }
        bf16x8 ap = __builtin_bit_cast(bf16x8, au);

        #pragma unroll
        for (int dc = 0; dc < 8; ++dc) {
            bf16x8 bv = __builtin_bit_cast(bf16x8,
                *(const us8*)&vt[(dc * 16 + lrow) * 40 + lgrp * 8]);
            accO[dc] = __builtin_amdgcn_mfma_f32_16x16x32_bf16(ap, bv, accO[dc], 0, 0, 0);
        }
    }

    float inv[4];
    #pragma unroll
    for (int r = 0; r < 4; ++r) inv[r] = 1.0f / l_r[r];
    float* op = og + (size_t)(b * NQ + q0 + wid * 16) * ND;
    #pragma unroll
    for (int dc = 0; dc < 8; ++dc) {
        #pragma unroll
        for (int r = 0; r < 4; ++r)
            op[(lgrp * 4 + r) * ND + dc * 16 + lrow] = accO[dc][r] * inv[r];
    }
}

extern "C" void kernel_launch(void* const* d_in, const int* in_sizes, int n_in,
                              void* d_out, int out_size, void* d_ws, size_t ws_size,
                              hipStream_t stream) {
    (void)in_sizes; (void)n_in; (void)out_size;
    const float* q  = (const float*)d_in[0];
    const float* k  = (const float*)d_in[1];
    const float* v  = (const float*)d_in[2];
    const int*   vl = (const int*)d_in[3];
    float* out = (float*)d_out;

    const size_t kvbytes = 2 * (size_t)NB * NK * ND * sizeof(unsigned short); // 16 MB
    if (ws_size >= kvbytes) {
        unsigned short* wk  = (unsigned short*)d_ws;
        unsigned short* wvt = wk + (size_t)NB * NK * ND;
        hipLaunchKernelGGL(prep_kv4, dim3(NTILE, NB), dim3(256), 0, stream, k, v, wk, wvt);
        hipLaunchKernelGGL(attn_fused13, dim3((NQ / 128) * NB), dim3(512), 0, stream,
                           q, vl, wk, wvt, out);
    } else {
        hipLaunchKernelGGL(attn_fused, dim3(NQ / 64, NB), dim3(256), 0, stream,
                           q, k, v, vl, out);
    }
}

// Round 14
// 56.927 us; speedup vs baseline: 9.0070x; 2.3080x over previous
//
#include <hip/hip_runtime.h>

// Problem constants (reference: B=16, Q=2048, K=2048, D=128, fp32, NEG=-1e6)
constexpr int NB = 16;
constexpr int NQ = 2048;
constexpr int NK = 2048;
constexpr int ND = 128;
constexpr int KVBLK = 64;                 // kv per tile
constexpr int NTILE = NK / KVBLK;         // 32
constexpr int TILE_USH = KVBLK * ND;      // 8192 ushorts = 16KB per tile
// 1/sqrt(128) * log2(e): QK^T emits log2-domain scores; exp -> v_exp_f32 (2^x)
constexpr float SCALE2 = 0.12751744751442557f;

typedef __attribute__((ext_vector_type(4))) float f4;
typedef __attribute__((ext_vector_type(16))) float f32x16;
typedef __attribute__((ext_vector_type(8))) unsigned short us8;
typedef __attribute__((ext_vector_type(8))) __bf16 bf16x8;
typedef __attribute__((ext_vector_type(4))) unsigned int u32x4;

static __device__ __forceinline__ unsigned short f2bf(float f) {
    unsigned u = __builtin_bit_cast(unsigned, f);
    u += 0x7fffu + ((u >> 16) & 1u);
    return (unsigned short)(u >> 16);
}
static __device__ __forceinline__ f4 splat4(float x) { f4 r = {x,x,x,x}; return r; }

static __device__ __forceinline__ float fexp2(float x) {
    float r;
    asm("v_exp_f32 %0, %1" : "=v"(r) : "v"(x));
    return r;
}

static __device__ __forceinline__ void load_lds16(const unsigned short* g, unsigned short* l) {
    __builtin_amdgcn_global_load_lds(
        (const __attribute__((address_space(1))) void*)g,
        (__attribute__((address_space(3))) void*)l,
        16, 0, 0);
}

static __device__ __forceinline__ unsigned cvt_pk_bf16(float lo, float hi) {
    unsigned r;
    asm("v_cvt_pk_bf16_f32 %0, %1, %2" : "=v"(r) : "v"(lo), "v"(hi));
    return r;
}

// ---------------------------------------------------------------------------
// Prep: per (batch, kv-tile=64) write K and V in lane-linear 32x32-MFMA
// fragment order (verified R5-R13):
//  K  (kv,d): off = ((kv>>5)*8 + (d>>4))*512 + ((d>>3)&1)*256 + (kv&31)*8 + (d&7)
//  V  (kv,d): off = ((kv>>4)*4 + (d>>5))*512 + ((kv>>3)&1)*256 + (d&31)*8 + (kv&7)
// grid (NTILE, NB), 256 threads
// ---------------------------------------------------------------------------
__global__ __launch_bounds__(256)
void prep_kv4(const float* __restrict__ kg, const float* __restrict__ vg,
              unsigned short* __restrict__ wk, unsigned short* __restrict__ wvt)
{
    const int b   = blockIdx.y;
    const int t   = blockIdx.x;
    const int kv0 = t * KVBLK;
    const int t0  = threadIdx.x;

    __shared__ __align__(16) unsigned short vl[64 * 136];

    {
        const int kv = t0 >> 2;
        const int c  = t0 & 3;
        const float* gp = kg + (size_t)(b * NK + kv0 + kv) * ND + c * 32;
        unsigned short* ob = wk + (size_t)(b * NTILE + t) * TILE_USH;
        #pragma unroll
        for (int g = 0; g < 4; ++g) {
            f4 f0 = *(const f4*)(gp + g * 8);
            f4 f1 = *(const f4*)(gp + g * 8 + 4);
            us8 w;
            #pragma unroll
            for (int i = 0; i < 4; ++i) { w[i] = f2bf(f0[i]); w[i+4] = f2bf(f1[i]); }
            const int d0 = c * 32 + g * 8;
            const int f  = (kv >> 5) * 8 + (d0 >> 4);
            const int off = f * 512 + ((d0 >> 3) & 1) * 256 + (kv & 31) * 8;
            *(us8*)(ob + off) = w;
        }
    }
    {
        const int kv = t0 >> 2;
        const int d0 = (t0 & 3) * 32;
        const float* gp = vg + (size_t)(b * NK + kv0 + kv) * ND + d0;
        unsigned short* lb = &vl[kv * 136 + d0];
        #pragma unroll
        for (int g = 0; g < 4; ++g) {
            f4 f0 = *(const f4*)(gp + g * 8);
            f4 f1 = *(const f4*)(gp + g * 8 + 4);
            us8 w;
            #pragma unroll
            for (int i = 0; i < 4; ++i) { w[i] = f2bf(f0[i]); w[i+4] = f2bf(f1[i]); }
            *(us8*)(lb + g * 8) = w;
        }
    }
    __syncthreads();
    {
        unsigned short* ob = wvt + (size_t)(b * NTILE + t) * TILE_USH;
        #pragma unroll
        for (int iter = 0; iter < 4; ++iter) {
            const int cid = iter * 256 + t0;
            const int f   = cid >> 6;
            const int l   = cid & 63;
            const int kb  = (f >> 2) * 16 + (l >> 5) * 8;
            const int d   = (f & 3) * 32 + (l & 31);
            us8 w;
            #pragma unroll
            for (int j = 0; j < 8; ++j) w[j] = vl[(kb + j) * 136 + d];
            *(us8*)(ob + cid * 8) = w;
        }
    }
}

// ---------------------------------------------------------------------------
// Fused attention v14: R11 structure (256-thr blocks, QBLK=64, 2 KV-groups x
// 2 q-waves, 64KB LDS, single-buffer DMA rotation, complementary-rank batch
// pairing) + log2-domain softmax (v_exp_f32 direct, no mul) and no setprio.
// ---------------------------------------------------------------------------
__global__ __launch_bounds__(256, 2)
void attn_fused14(const float* __restrict__ qg, const int* __restrict__ vlen,
                  const unsigned short* __restrict__ wk,
                  const unsigned short* __restrict__ wvt,
                  float* __restrict__ og)
{
    const int bid  = blockIdx.x;
    const int half = bid >> 8;      // 0: long ranks 0-7, 1: short ranks 15-8
    const int j    = bid & 255;
    const int rank = half ? (15 - (j & 7)) : (j & 7);
    const int qc   = j >> 3;        // 0..31
    const int q0   = qc * 64;

    // batch with this Leff-descending rank (ties by index)
    int b = 0;
    {
        int Ls[16];
        #pragma unroll
        for (int i = 0; i < 16; ++i) {
            const int v = vlen[i];
            Ls[i] = (v <= 0) ? NK : v;
        }
        #pragma unroll
        for (int bb = 0; bb < 16; ++bb) {
            int r = 0;
            #pragma unroll
            for (int cc = 0; cc < 16; ++cc)
                r += (Ls[cc] > Ls[bb] || (Ls[cc] == Ls[bb] && cc < bb)) ? 1 : 0;
            if (r == rank) b = bb;
        }
    }

    const int tid  = threadIdx.x;
    const int wid  = tid >> 6;
    const int grp  = wid >> 1;     // KV-split group 0/1
    const int qw   = wid & 1;      // q-chunk within block (32 rows each)
    const int lane = tid & 63;
    const int lq   = lane & 31;
    const int hi   = lane >> 5;

    const int L = vlen[b];
    const bool uniform = (L <= 0);
    const int Leff = uniform ? NK : L;
    const int ntiles = (Leff + KVBLK - 1) / KVBLK;
    const int ng    = (ntiles + 1 - grp) >> 1;
    const int niter = (ntiles + 1) >> 1;

    // [group][K 16KB | V 16KB] single-buffered = 64 KB total
    __shared__ __align__(16) unsigned short smem[2][2 * TILE_USH];

    // ---- Q fragments (B-operand), scaled by 1/sqrt(D)*log2(e)
    bf16x8 aq[8];
    {
        const float* qp = qg + (size_t)(b * NQ + q0 + qw * 32 + lq) * ND + hi * 8;
        #pragma unroll
        for (int c = 0; c < 8; ++c) {
            f4 f0 = *(const f4*)(qp + c * 16);
            f4 f1 = *(const f4*)(qp + c * 16 + 4);
            us8 u;
            #pragma unroll
            for (int i = 0; i < 4; ++i) {
                u[i]     = f2bf(f0[i] * SCALE2);
                u[i + 4] = f2bf(f1[i] * SCALE2);
            }
            aq[c] = __builtin_bit_cast(bf16x8, u);
        }
    }

    const unsigned short* kbg = wk  + (size_t)b * NTILE * TILE_USH;
    const unsigned short* vbg = wvt + (size_t)b * NTILE * TILE_USH;

    // staging: wave qw=0 stages K (16KB), qw=1 stages V (16KB), 16 x 1KB DMA
    const unsigned short* sbase = qw ? vbg : kbg;
    unsigned short* sdst = &smem[grp][qw * 8192];
    const int s_off = lane * 8;

    float m_r = -__builtin_inff();
    float l_r = 0.f;
    f32x16 accO[4];
    #pragma unroll
    for (int dc = 0; dc < 4; ++dc)
        #pragma unroll
        for (int r = 0; r < 16; ++r) accO[dc][r] = 0.f;

    // ---- prologue: stage tile grp
    if (grp < ntiles) {
        const unsigned short* src = sbase + (size_t)grp * TILE_USH + s_off;
        #pragma unroll
        for (int jj = 0; jj < 16; ++jj) load_lds16(src + jj * 512, sdst + jj * 512);
    }
    __syncthreads();

    for (int i = 0; i < niter; ++i) {
        const int tile = 2 * i + grp;
        const unsigned short* kl  = &smem[grp][0];
        const unsigned short* vl2 = &smem[grp][8192];
        const bool act = (i < ng);

        us8 kf[16], vf[16];
        f32x16 sA, sB;
        if (act) {
            // ---- K frags -> regs, QK^T (swapped: S^T[64k x 32q], log2 domain)
            #pragma unroll
            for (int c = 0; c < 16; ++c)
                kf[c] = *(const us8*)&kl[c * 512 + lane * 8];
            #pragma unroll
            for (int r = 0; r < 16; ++r) { sA[r] = 0.f; sB[r] = 0.f; }
            #pragma unroll
            for (int c = 0; c < 8; ++c) {
                sA = __builtin_amdgcn_mfma_f32_32x32x16_bf16(
                    __builtin_bit_cast(bf16x8, kf[c]), aq[c], sA, 0, 0, 0);
                sB = __builtin_amdgcn_mfma_f32_32x32x16_bf16(
                    __builtin_bit_cast(bf16x8, kf[8 + c]), aq[c], sB, 0, 0, 0);
            }
            __builtin_amdgcn_sched_barrier(0);   // VGPR peak control
            // ---- V frags -> regs
            #pragma unroll
            for (int f = 0; f < 16; ++f)
                vf[f] = *(const us8*)&vl2[f * 512 + lane * 8];
        }

        // BARRIER A: all ds_reads drained (implicit lgkmcnt(0)) -> buffer free
        __syncthreads();

        // ---- issue next tile's DMA into the (now free) buffer
        {
            const int tn = tile + 2;
            if (tn < ntiles) {
                const unsigned short* src = sbase + (size_t)tn * TILE_USH + s_off;
                #pragma unroll
                for (int jj = 0; jj < 16; ++jj) load_lds16(src + jj * 512, sdst + jj * 512);
            }
        }

        if (act) {
            const int kv0 = tile * KVBLK;

            // ---- mask (rows = k)
            if (uniform) {
                #pragma unroll
                for (int r = 0; r < 16; ++r) { sA[r] = 0.f; sB[r] = 0.f; }
            } else {
                const int lim0 = L - kv0 - 4 * hi;
                const int lim1 = lim0 - 32;
                #pragma unroll
                for (int r = 0; r < 16; ++r) {
                    const int rc = (r & 3) + 8 * (r >> 2);
                    sA[r] = (rc >= lim0) ? -__builtin_inff() : sA[r];
                    sB[r] = (rc >= lim1) ? -__builtin_inff() : sB[r];
                }
            }

            // ---- in-register softmax for q = lq (log2 domain)
            float mx[8];
            #pragma unroll
            for (int i2 = 0; i2 < 8; ++i2)
                mx[i2] = fmaxf(fmaxf(sA[i2], sA[i2 + 8]), fmaxf(sB[i2], sB[i2 + 8]));
            #pragma unroll
            for (int i2 = 0; i2 < 4; ++i2) mx[i2] = fmaxf(mx[i2], mx[i2 + 4]);
            float pm = fmaxf(fmaxf(mx[0], mx[1]), fmaxf(mx[2], mx[3]));
            float pmax = fmaxf(pm, __shfl_xor(pm, 32));

            // T13: rescale only when some q-row got a new max
            if (__any(pmax > m_r)) {
                const float mnew = fmaxf(m_r, pmax);
                const float sc = fexp2(m_r - mnew);
                m_r = mnew;
                l_r *= sc;
                #pragma unroll
                for (int r = 0; r < 16; ++r) {
                    const int src = ((r & 3) + 8 * (r >> 2) + 4 * hi) + (lane & 32);
                    const float scr = __shfl(sc, src);
                    accO[0][r] *= scr; accO[1][r] *= scr;
                    accO[2][r] *= scr; accO[3][r] *= scr;
                }
            }

            // ---- 2^x + row-sum
            float p0[16], p1[16];
            #pragma unroll
            for (int r = 0; r < 16; ++r) {
                p0[r] = fexp2(sA[r] - m_r);
                p1[r] = fexp2(sB[r] - m_r);
            }
            float sm[8];
            #pragma unroll
            for (int i2 = 0; i2 < 8; ++i2)
                sm[i2] = (p0[i2] + p0[i2 + 8]) + (p1[i2] + p1[i2 + 8]);
            #pragma unroll
            for (int i2 = 0; i2 < 4; ++i2) sm[i2] += sm[i2 + 4];
            float rsum = (sm[0] + sm[1]) + (sm[2] + sm[3]);
            rsum += __shfl_xor(rsum, 32);
            l_r += rsum;

            // ---- P -> bf16 packed words; half-exchange builds PV A-frags
            unsigned cw[16];
            #pragma unroll
            for (int i2 = 0; i2 < 8; ++i2) cw[i2] = cvt_pk_bf16(p0[2 * i2], p0[2 * i2 + 1]);
            #pragma unroll
            for (int i2 = 0; i2 < 8; ++i2) cw[8 + i2] = cvt_pk_bf16(p1[2 * i2], p1[2 * i2 + 1]);

            bf16x8 pa[4];
            #pragma unroll
            for (int ks = 0; ks < 4; ++ks) {
                const int a = 4 * ks;
                const unsigned u = hi ? cw[a]     : cw[a + 2];
                const unsigned v = hi ? cw[a + 1] : cw[a + 3];
                const unsigned up = __shfl_xor((int)u, 32);
                const unsigned vp = __shfl_xor((int)v, 32);
                u32x4 w;
                w[0] = hi ? up        : cw[a];
                w[1] = hi ? vp        : cw[a + 1];
                w[2] = hi ? cw[a + 2] : up;
                w[3] = hi ? cw[a + 3] : vp;
                pa[ks] = __builtin_bit_cast(bf16x8, w);
            }

            // ---- PV from regs
            #pragma unroll
            for (int dc = 0; dc < 4; ++dc) {
                #pragma unroll
                for (int ks = 0; ks < 4; ++ks) {
                    accO[dc] = __builtin_amdgcn_mfma_f32_32x32x16_bf16(
                        pa[ks], __builtin_bit_cast(bf16x8, vf[ks * 4 + dc]), accO[dc], 0, 0, 0);
                }
            }
        }

        // BARRIER B: implicit vmcnt(0) lands this iteration's DMA
        __syncthreads();
    }

    // ---- merge epilogue: group1 -> LDS (32KB accO + m/l), group0 combines
    float* accb = (float*)&smem[0][0];
    float* mlb  = accb + 8192;            // 128 floats
    if (grp == 1) {
        #pragma unroll
        for (int dc = 0; dc < 4; ++dc) {
            #pragma unroll
            for (int q4 = 0; q4 < 4; ++q4) {
                f4 v;
                #pragma unroll
                for (int c = 0; c < 4; ++c) v[c] = accO[dc][q4 * 4 + c];
                *(f4*)&accb[(((qw * 16 + dc * 4 + q4) * 64) + lane) * 4] = v;
            }
        }
        if (hi == 0) {
            mlb[qw * 32 + lq]      = m_r;
            mlb[64 + qw * 32 + lq] = l_r;
        }
    }
    __syncthreads();
    if (grp == 0) {
        const float m1 = mlb[qw * 32 + lq];
        const float l1 = mlb[64 + qw * 32 + lq];
        const float m  = fmaxf(m_r, m1);
        const float a0 = fexp2(m_r - m), a1 = fexp2(m1 - m);
        const float linv = 1.0f / (a0 * l_r + a1 * l1);
        const float s0v = a0 * linv, s1v = a1 * linv;
        float* ob = og + (size_t)(b * NQ + q0 + qw * 32) * ND;
        #pragma unroll
        for (int dc = 0; dc < 4; ++dc) {
            #pragma unroll
            for (int q4 = 0; q4 < 4; ++q4) {
                f4 o1 = *(const f4*)&accb[(((qw * 16 + dc * 4 + q4) * 64) + lane) * 4];
                #pragma unroll
                for (int c = 0; c < 4; ++c) {
                    const int r = q4 * 4 + c;
                    const int row = c + 8 * q4 + 4 * hi;
                    const float s0r = __shfl(s0v, row + (lane & 32));
                    const float s1r = __shfl(s1v, row + (lane & 32));
                    ob[(size_t)row * ND + dc * 32 + lq] = accO[dc][r] * s0r + o1[c] * s1r;
                }
            }
        }
    }
}

// ---------------------------------------------------------------------------
// Fallback (R1 kernel): used only if ws_size < 16 MB
// ---------------------------------------------------------------------------
__global__ __launch_bounds__(256, 2)
void attn_fused(const float* __restrict__ qg, const float* __restrict__ kg,
                const float* __restrict__ vg, const int* __restrict__ vlen,
                float* __restrict__ og)
{
    const int b    = blockIdx.y;
    const int q0   = blockIdx.x * 64;
    const int tid  = threadIdx.x;
    const int wid  = tid >> 6;
    const int lane = tid & 63;
    const int lrow = lane & 15;
    const int lgrp = lane >> 4;
    constexpr float SCALE = 0.08838834764831844f;

    const int L = vlen[b];
    const bool uniform = (L <= 0);
    const int Leff = uniform ? NK : L;
    const int nt32 = (Leff + 31) / 32;

    __shared__ __align__(16) unsigned short kt[32 * 136];
    __shared__ __align__(16) unsigned short vt[128 * 40];
    __shared__ __align__(16) float pt[4][16 * 36];

    bf16x8 aqf[4];
    {
        const float* qp = qg + (size_t)(b * NQ + q0 + wid * 16 + lrow) * ND + lgrp * 8;
        #pragma unroll
        for (int c = 0; c < 4; ++c) {
            f4 f0 = *(const f4*)(qp + c * 32);
            f4 f1 = *(const f4*)(qp + c * 32 + 4);
            us8 u;
            #pragma unroll
            for (int i = 0; i < 4; ++i) {
                u[i]     = f2bf(f0[i] * SCALE);
                u[i + 4] = f2bf(f1[i] * SCALE);
            }
            aqf[c] = __builtin_bit_cast(bf16x8, u);
        }
    }

    float m_r[4], l_r[4];
    f4 accO[8];
    #pragma unroll
    for (int r = 0; r < 4; ++r) { m_r[r] = -__builtin_inff(); l_r[r] = 0.f; }
    #pragma unroll
    for (int dc = 0; dc < 8; ++dc) accO[dc] = splat4(0.f);

    for (int t = 0; t < nt32; ++t) {
        const int kv0 = t * 32;
        __syncthreads();
        {
            const int r  = tid >> 3;
            const int c0 = (tid & 7) * 16;
            const float* gp = kg + (size_t)(b * NK + kv0 + r) * ND + c0;
            f4 f0 = *(const f4*)(gp);
            f4 f1 = *(const f4*)(gp + 4);
            f4 f2 = *(const f4*)(gp + 8);
            f4 f3 = *(const f4*)(gp + 12);
            us8 w0, w1;
            #pragma unroll
            for (int i = 0; i < 4; ++i) {
                w0[i]     = f2bf(f0[i]);
                w0[i + 4] = f2bf(f1[i]);
                w1[i]     = f2bf(f2[i]);
                w1[i + 4] = f2bf(f3[i]);
            }
            unsigned short* dst = &kt[r * 136 + c0];
            *(us8*)(dst)     = w0;
            *(us8*)(dst + 8) = w1;
        }
        {
            const int d  = tid & 127;
            const int g2 = tid >> 7;
            const float* gp = vg + (size_t)(b * NK + kv0 + g2 * 16) * ND + d;
            us8 w0, w1;
            #pragma unroll
            for (int jj = 0; jj < 8; ++jj) {
                w0[jj] = f2bf(gp[(size_t)jj * ND]);
                w1[jj] = f2bf(gp[(size_t)(jj + 8) * ND]);
            }
            unsigned short* dst = &vt[d * 40 + g2 * 16];
            *(us8*)(dst)     = w0;
            *(us8*)(dst + 8) = w1;
        }
        __syncthreads();

        f4 s0 = splat4(0.f), s1 = splat4(0.f);
        #pragma unroll
        for (int c = 0; c < 4; ++c) {
            bf16x8 bk0 = __builtin_bit_cast(bf16x8,
                *(const us8*)&kt[lrow * 136 + c * 32 + lgrp * 8]);
            s0 = __builtin_amdgcn_mfma_f32_16x16x32_bf16(aqf[c], bk0, s0, 0, 0, 0);
            bf16x8 bk1 = __builtin_bit_cast(bf16x8,
                *(const us8*)&kt[(16 + lrow) * 136 + c * 32 + lgrp * 8]);
            s1 = __builtin_amdgcn_mfma_f32_16x16x32_bf16(aqf[c], bk1, s1, 0, 0, 0);
        }

        const int col0 = kv0 + lrow;
        if (uniform) {
            s0 = splat4(0.f);
            s1 = splat4(0.f);
        } else {
            if (col0 >= L)      s0 = splat4(-__builtin_inff());
            if (col0 + 16 >= L) s1 = splat4(-__builtin_inff());
        }

        float pm[4];
        #pragma unroll
        for (int r = 0; r < 4; ++r) pm[r] = fmaxf(s0[r], s1[r]);
        #pragma unroll
        for (int off = 8; off > 0; off >>= 1) {
            #pragma unroll
            for (int r = 0; r < 4; ++r)
                pm[r] = fmaxf(pm[r], __shfl_xor(pm[r], off));
        }
        float pr0[4], pr1[4], rs[4], sc[4];
        #pragma unroll
        for (int r = 0; r < 4; ++r) {
            float mn = fmaxf(m_r[r], pm[r]);
            sc[r]  = __expf(m_r[r] - mn);
            m_r[r] = mn;
            pr0[r] = __expf(s0[r] - mn);
            pr1[r] = __expf(s1[r] - mn);
            rs[r]  = pr0[r] + pr1[r];
        }
        #pragma unroll
        for (int off = 8; off > 0; off >>= 1) {
            #pragma unroll
            for (int r = 0; r < 4; ++r)
                rs[r] += __shfl_xor(rs[r], off);
        }
        #pragma unroll
        for (int r = 0; r < 4; ++r) l_r[r] = l_r[r] * sc[r] + rs[r];
        #pragma unroll
        for (int dc = 0; dc < 8; ++dc) {
            #pragma unroll
            for (int r = 0; r < 4; ++r) accO[dc][r] *= sc[r];
        }

        float* pw = pt[wid];
        #pragma unroll
        for (int r = 0; r < 4; ++r) {
            pw[(lgrp * 4 + r) * 36 + lrow]      = pr0[r];
            pw[(lgrp * 4 + r) * 36 + 16 + lrow] = pr1[r];
        }
        asm volatile("s_waitcnt lgkmcnt(0)" ::: "memory");
        f4 a0 = *(const f4*)&pw[lrow * 36 + lgrp * 8];
        f4 a1 = *(const f4*)&pw[lrow * 36 + lgrp * 8 + 4];
        us8 au;
        #pragma unroll
        for (int i = 0; i < 4; ++i) { au[i] = f2bf(a0[i]); au[i + 4] = f2bf(a1[i]); }
        bf16x8 ap = __builtin_bit_cast(bf16x8, au);

        #pragma unroll
        for (int dc = 0; dc < 8; ++dc) {
            bf16x8 bv = __builtin_bit_cast(bf16x8,
                *(const us8*)&vt[(dc * 16 + lrow) * 40 + lgrp * 8]);
            accO[dc] = __builtin_amdgcn_mfma_f32_16x16x32_bf16(ap, bv, accO[dc], 0, 0, 0);
        }
    }

    float inv[4];
    #pragma unroll
    for (int r = 0; r < 4; ++r) inv[r] = 1.0f / l_r[r];
    float* op = og + (size_t)(b * NQ + q0 + wid * 16) * ND;
    #pragma unroll
    for (int dc = 0; dc < 8; ++dc) {
        #pragma unroll
        for (int r = 0; r < 4; ++r)
            op[(lgrp * 4 + r) * ND + dc * 16 + lrow] = accO[dc][r] * inv[r];
    }
}

extern "C" void kernel_launch(void* const* d_in, const int* in_sizes, int n_in,
                              void* d_out, int out_size, void* d_ws, size_t ws_size,
                              hipStream_t stream) {
    (void)in_sizes; (void)n_in; (void)out_size;
    const float* q  = (const float*)d_in[0];
    const float* k  = (const float*)d_in[1];
    const float* v  = (const float*)d_in[2];
    const int*   vl = (const int*)d_in[3];
    float* out = (float*)d_out;

    const size_t kvbytes = 2 * (size_t)NB * NK * ND * sizeof(unsigned short); // 16 MB
    if (ws_size >= kvbytes) {
        unsigned short* wk  = (unsigned short*)d_ws;
        unsigned short* wvt = wk + (size_t)NB * NK * ND;
        hipLaunchKernelGGL(prep_kv4, dim3(NTILE, NB), dim3(256), 0, stream, k, v, wk, wvt);
        hipLaunchKernelGGL(attn_fused14, dim3((NQ / 64) * NB), dim3(256), 0, stream,
                           q, vl, wk, wvt, out);
    } else {
        hipLaunchKernelGGL(attn_fused, dim3(NQ / 64, NB), dim3(256), 0, stream,
                           q, k, v, vl, out);
    }
}